// Round 7
// baseline (7098.241 us; speedup 1.0000x reference)
//
#include <hip/hip_runtime.h>
#include <hip/hip_fp16.h>

typedef __attribute__((ext_vector_type(2))) _Float16 half2v;
typedef __attribute__((ext_vector_type(2))) __fp16   fp16x2;

#define SEQ     512
#define THREADS 512

// ws: uint4 wsAll[64][3584]; col c: [0,512)=Wq, [512,2048)=Wh(r,z,n), [2048,3584)=Wx(r,z,n)
#define SYNC_OFF 3670016
// sync region (bytes from SYNC_OFF):
// flagH u32[256]@0 ; flagA u32[256]@1024 ; flagF u32[256]@2048
// Hbuf u32[2][64][256]@3072 (131072) -> 134144
// Pbuf f32[2][16][16][12]@134144 (24576) -> 158720
// pooled f32[64][512]@158720 -> 289792 ; fc1 f32[64][512]@289792 -> 420864

__device__ inline unsigned int pack2f16(float a, float b) {
    fp16x2 p = __builtin_amdgcn_cvt_pkrtz(a, b);
    return __builtin_bit_cast(unsigned int, p);
}
__device__ inline float fdot2u(unsigned int a, unsigned int b, float acc) {
    return __builtin_amdgcn_fdot2(__builtin_bit_cast(half2v, a),
                                  __builtin_bit_cast(half2v, b), acc, false);
}
__device__ inline float dot4(uint4 h, uint4 w, float acc) {
    acc = fdot2u(h.x, w.x, acc); acc = fdot2u(h.y, w.y, acc);
    acc = fdot2u(h.z, w.z, acc); acc = fdot2u(h.w, w.w, acc);
    return acc;
}
__device__ inline float fsigmoid(float x) { return 1.f / (1.f + __expf(-x)); }
__device__ inline float ftanhf(float x) {
    float e = __expf(-2.f * fabsf(x));
    float t = (1.f - e) / (1.f + e);
    return copysignf(t, x);
}
__device__ inline void vmem_fence() { asm volatile("s_waitcnt vmcnt(0)" ::: "memory"); }
__device__ inline unsigned a_ld(unsigned* p) {
    return __hip_atomic_load(p, __ATOMIC_RELAXED, __HIP_MEMORY_SCOPE_AGENT);
}
__device__ inline void a_st(unsigned* p, unsigned v) {
    __hip_atomic_store(p, v, __ATOMIC_RELAXED, __HIP_MEMORY_SCOPE_AGENT);
}
__device__ inline float a_ldf(float* p) {
    return __hip_atomic_load(p, __ATOMIC_RELAXED, __HIP_MEMORY_SCOPE_AGENT);
}
__device__ inline void a_stf(float* p, float v) {
    __hip_atomic_store(p, v, __ATOMIC_RELAXED, __HIP_MEMORY_SCOPE_AGENT);
}

// unified pack: ws[m4][c], m4<64 covers K dims [8*m4,+8) as f16 pairs in uint4
__global__ __launch_bounds__(256)
void pack_weights(const float* __restrict__ Wq,
                  const float* __restrict__ Wx,
                  const float* __restrict__ Wh,
                  uint4* __restrict__ ws) {
    int tid = blockIdx.x * blockDim.x + threadIdx.x;  // 0..229375
    int m4 = tid / 3584;
    int c  = tid - m4 * 3584;
    const float* s; int ld;
    if (c < 512)       { s = Wq + c;          ld = 512;  }
    else if (c < 2048) { s = Wh + (c - 512);  ld = 1536; }
    else               { s = Wx + (c - 2048); ld = 1536; }
    s += (size_t)(m4 * 8) * ld;
    uint4 o;
    o.x = pack2f16(s[0], s[(size_t)ld]);
    o.y = pack2f16(s[2 * (size_t)ld], s[3 * (size_t)ld]);
    o.z = pack2f16(s[4 * (size_t)ld], s[5 * (size_t)ld]);
    o.w = pack2f16(s[6 * (size_t)ld], s[7 * (size_t)ld]);
    ws[tid] = o;
}

// 256 blocks. xcd = blk&7, ii = blk>>3; gid = xcd*2 + (ii>>4) (16 groups, XCD-local),
// bid = ii&15. Group gid owns batches 4*gid..+4. Block owns dims/cols [bid*32,+32).
// All weights in registers. 2 syncs/step (h, partial-scores).
__global__ __launch_bounds__(THREADS)
void gru_scan(const int* __restrict__ xtok, const float* __restrict__ emb,
              const uint4* __restrict__ ws, const float* __restrict__ bx,
              const float* __restrict__ bh, const float* __restrict__ W1,
              const float* __restrict__ b1, const float* __restrict__ W2,
              const float* __restrict__ b2, float* __restrict__ out)
{
    const int blk  = blockIdx.x;
    const int xcd  = blk & 7;
    const int ii   = blk >> 3;
    const int gid  = xcd * 2 + (ii >> 4);   // 0..15
    const int bid  = ii & 15;               // 0..15
    const int tid  = threadIdx.x;
    const int lane = tid & 63;
    const int w    = tid >> 6;

    char* syncb = (char*)ws + SYNC_OFF;
    unsigned* flagH = (unsigned*)syncb;
    unsigned* flagA = (unsigned*)(syncb + 1024);
    unsigned* flagF = (unsigned*)(syncb + 2048);
    unsigned* Hbuf  = (unsigned*)(syncb + 3072);
    float* Pbuf     = (float*)(syncb + 134144);
    float* pooled_g = (float*)(syncb + 158720);
    float* fc1_g    = (float*)(syncb + 289792);

    __shared__ uint4 lds_h[4][64];     // h(t-1) f16 pairs, 4 batches
    __shared__ uint4 lds_ctx[4][64];   // ctx f16 pairs
    __shared__ float outA[128][4];     // [col][batch]: 0..31 q, 32..63 ghr, 64..95 ghz, 96..127 ghn
    __shared__ float outB[96][4];      // 0..31 gxr, 32..63 gxz, 64..95 gxn
    __shared__ float a_all[4][8][3];

    // ---- register weights ----
    const int kq  = lane & 3;          // K-quarter
    const int csA = lane >> 2;         // 0..15
    const int cA  = w * 16 + csA;      // 0..127
    const int gcA = (cA < 32) ? bid * 32 + cA
                  : 512 + ((cA - 32) >> 5) * 512 + bid * 32 + ((cA - 32) & 31);
    uint4 wA[16];
    #pragma unroll
    for (int kk = 0; kk < 16; ++kk) wA[kk] = ws[(size_t)(kq * 16 + kk) * 3584 + gcA];
    const bool actB = csA < 12;
    const int cB  = w * 12 + csA;      // 0..95 when actB
    const int gcB = 2048 + (cB >> 5) * 512 + bid * 32 + (cB & 31);
    uint4 wB[16];
    if (actB) {
        #pragma unroll
        for (int kk = 0; kk < 16; ++kk) wB[kk] = ws[(size_t)(kq * 16 + kk) * 3584 + gcB];
    }

    // biases for pointwise threads (tid<128: b=tid&3, m=tid>>2)
    float bhr = 0, bhz = 0, bhn = 0, bxr = 0, bxz = 0, bxn = 0;
    if (tid < 128) {
        int m = tid >> 2, cg = bid * 32 + m;
        bhr = bh[cg]; bhz = bh[512 + cg]; bhn = bh[1024 + cg];
        bxr = bx[cg]; bxz = bx[512 + cg]; bxn = bx[1024 + cg];
    }

    // ctx duty: wave w -> batch bw = w>>1, half dh = w&1, dims d0..d0+3
    const int bw = w >> 1, dh = w & 1;
    const int d0 = dh * 256 + lane * 4;
    const int gbw = gid * 4 + bw;
    float4 r0 = {0, 0, 0, 0}, r1 = {0, 0, 0, 0};
    // wave0 score k rolling (lane&31 -> dim bid*32 + (lane&31))
    float k0q[4] = {0, 0, 0, 0}, k1q[4] = {0, 0, 0, 0};

    float hprev = 0.f, pooledv = 0.f;

    for (int t = 0; t < SEQ; ++t) {
        const int par = t & 1;

        // ---- prefetch (before h-wait; loads fly during spin) ----
        int tokw = xtok[gbw * SEQ + t];
        float4 r2 = *(const float4*)(emb + (size_t)tokw * 512 + d0);
        float k2q[4];
        if (w == 0) {
            int l32 = lane & 31;
            #pragma unroll
            for (int b = 0; b < 4; ++b) {
                int tk = xtok[(gid * 4 + b) * SEQ + t];
                k2q[b] = emb[(size_t)tk * 512 + bid * 32 + l32];
            }
        } else { k2q[0] = k2q[1] = k2q[2] = k2q[3] = 0.f; }

        // ---- wait: h(t-1) from all 16 blocks ----
        if (w == 0) {
            bool done = lane >= 16;
            while (!__all(done)) {
                if (!done) done = (a_ld(&flagH[gid * 16 + lane]) >= (unsigned)t);
                if (!__all(done)) __builtin_amdgcn_s_sleep(1);
            }
        }
        __syncthreads();                                   // S1
        if (tid < 256) {
            int bb = tid >> 6, c4 = tid & 63;
            unsigned* s = Hbuf + (size_t)(par ^ 1) * 16384 + (gid * 4 + bb) * 256 + c4 * 4;
            uint4 v; v.x = a_ld(s); v.y = a_ld(s + 1); v.z = a_ld(s + 2); v.w = a_ld(s + 3);
            lds_h[bb][c4] = v;
        }
        __syncthreads();                                   // S2

        // ---- GEMM-A: [q|ghr|ghz|ghn] = h @ W, reg weights ----
        {
            float a0 = 0, a1 = 0, a2 = 0, a3 = 0;
            #pragma unroll
            for (int kk = 0; kk < 16; ++kk) {
                int ix = kq * 16 + kk;
                uint4 h0 = lds_h[0][ix], h1 = lds_h[1][ix];
                uint4 h2 = lds_h[2][ix], h3 = lds_h[3][ix];
                a0 = dot4(h0, wA[kk], a0); a1 = dot4(h1, wA[kk], a1);
                a2 = dot4(h2, wA[kk], a2); a3 = dot4(h3, wA[kk], a3);
            }
            a0 += __shfl_xor(a0, 1); a0 += __shfl_xor(a0, 2);
            a1 += __shfl_xor(a1, 1); a1 += __shfl_xor(a1, 2);
            a2 += __shfl_xor(a2, 1); a2 += __shfl_xor(a2, 2);
            a3 += __shfl_xor(a3, 1); a3 += __shfl_xor(a3, 2);
            if (kq == 0) { float4 o = {a0, a1, a2, a3}; *(float4*)&outA[cA][0] = o; }
        }
        __syncthreads();                                   // S3

        // ---- wave0: pscores -> publish -> wait -> sum+softmax -> a_all ----
        if (w == 0) {
            float4 qv = *(float4*)&outA[lane & 31][0];
            float p[12];
            p[0] = qv.x * k0q[0]; p[1]  = qv.x * k1q[0]; p[2]  = qv.x * k2q[0];
            p[3] = qv.y * k0q[1]; p[4]  = qv.y * k1q[1]; p[5]  = qv.y * k2q[1];
            p[6] = qv.z * k0q[2]; p[7]  = qv.z * k1q[2]; p[8]  = qv.z * k2q[2];
            p[9] = qv.w * k0q[3]; p[10] = qv.w * k1q[3]; p[11] = qv.w * k2q[3];
            #pragma unroll
            for (int off = 1; off < 32; off <<= 1) {
                #pragma unroll
                for (int r = 0; r < 12; ++r) p[r] += __shfl_xor(p[r], off);
            }
            if (lane == 0) {
                float* pb = Pbuf + ((size_t)(par * 16 + gid) * 16 + bid) * 12;
                #pragma unroll
                for (int r = 0; r < 12; ++r) a_stf(pb + r, p[r]);
            }
            vmem_fence();
            if (lane == 0) a_st(&flagA[gid * 16 + bid], (unsigned)(t + 1));
            bool done = lane >= 16;
            while (!__all(done)) {
                if (!done) done = (a_ld(&flagA[gid * 16 + lane]) >= (unsigned)(t + 1));
                if (!__all(done)) __builtin_amdgcn_s_sleep(1);
            }
            if (lane < 32) {
                int b = lane >> 3, n = lane & 7;
                float* base = Pbuf + (size_t)(par * 16 + gid) * 16 * 12;
                float s0 = a_ldf(base + (2 * n) * 12 + b * 3 + 0) + a_ldf(base + (2 * n + 1) * 12 + b * 3 + 0);
                float s1 = a_ldf(base + (2 * n) * 12 + b * 3 + 1) + a_ldf(base + (2 * n + 1) * 12 + b * 3 + 1);
                float s2 = a_ldf(base + (2 * n) * 12 + b * 3 + 2) + a_ldf(base + (2 * n + 1) * 12 + b * 3 + 2);
                s0 *= 0.125f; s1 *= 0.125f; s2 *= 0.125f;
                float mx = fmaxf(s0, fmaxf(s1, s2));
                float e0 = __expf(s0 - mx), e1 = __expf(s1 - mx), e2 = __expf(s2 - mx);
                float inv = 1.f / (e0 + e1 + e2);
                a_all[b][n][0] = e0 * inv; a_all[b][n][1] = e1 * inv; a_all[b][n][2] = e2 * inv;
            }
        }
        __syncthreads();                                   // S4

        // ---- ctx build (window rows in regs) ----
        {
            int head = d0 >> 6;
            float aa0 = a_all[bw][head][0], aa1 = a_all[bw][head][1], aa2 = a_all[bw][head][2];
            float c0 = aa0 * r0.x + aa1 * r1.x + aa2 * r2.x;
            float c1 = aa0 * r0.y + aa1 * r1.y + aa2 * r2.y;
            float c2 = aa0 * r0.z + aa1 * r1.z + aa2 * r2.z;
            float c3 = aa0 * r0.w + aa1 * r1.w + aa2 * r2.w;
            unsigned* cu = (unsigned*)&lds_ctx[bw][0];
            uint2 pk = { pack2f16(c0, c1), pack2f16(c2, c3) };
            *(uint2*)&cu[dh * 128 + lane * 2] = pk;
        }
        __syncthreads();                                   // S5

        // ---- GEMM-B: [gxr|gxz|gxn] = ctx @ Wx, reg weights ----
        if (actB) {
            float a0 = 0, a1 = 0, a2 = 0, a3 = 0;
            #pragma unroll
            for (int kk = 0; kk < 16; ++kk) {
                int ix = kq * 16 + kk;
                uint4 h0 = lds_ctx[0][ix], h1 = lds_ctx[1][ix];
                uint4 h2 = lds_ctx[2][ix], h3 = lds_ctx[3][ix];
                a0 = dot4(h0, wB[kk], a0); a1 = dot4(h1, wB[kk], a1);
                a2 = dot4(h2, wB[kk], a2); a3 = dot4(h3, wB[kk], a3);
            }
            a0 += __shfl_xor(a0, 1); a0 += __shfl_xor(a0, 2);
            a1 += __shfl_xor(a1, 1); a1 += __shfl_xor(a1, 2);
            a2 += __shfl_xor(a2, 1); a2 += __shfl_xor(a2, 2);
            a3 += __shfl_xor(a3, 1); a3 += __shfl_xor(a3, 2);
            if (kq == 0) { float4 o = {a0, a1, a2, a3}; *(float4*)&outB[cB][0] = o; }
        }
        __syncthreads();                                   // S6

        // ---- GRU pointwise + h publish ----
        if (tid < 128) {
            int b = tid & 3, m = tid >> 2;
            float ghr = outA[32 + m][b], ghz = outA[64 + m][b], ghn = outA[96 + m][b];
            float gxr = outB[m][b],      gxz = outB[32 + m][b], gxn = outB[64 + m][b];
            float r = fsigmoid(gxr + bxr + ghr + bhr);
            float z = fsigmoid(gxz + bxz + ghz + bhz);
            float n = ftanhf(gxn + bxn + r * (ghn + bhn));
            float hnew = (1.f - z) * n + z * hprev;
            hprev = hnew; pooledv += hnew;
            float hnext = __shfl_down(hnew, 4);
            if (!(m & 1))
                a_st(&Hbuf[(size_t)par * 16384 + (gid * 4 + b) * 256 + bid * 16 + (m >> 1)],
                     pack2f16(hnew, hnext));
        }
        vmem_fence();
        __syncthreads();                                   // S7
        if (tid == 0) a_st(&flagH[gid * 16 + bid], (unsigned)(t + 1));

        // roll window regs
        r0 = r1; r1 = r2;
        if (w == 0) {
            #pragma unroll
            for (int b = 0; b < 4; ++b) { k0q[b] = k1q[b]; k1q[b] = k2q[b]; }
        }
    }

    // ======== epilogue ========
    if (tid < 128) {
        int b = tid & 3, m = tid >> 2;
        a_stf(&pooled_g[(size_t)(gid * 4 + b) * 512 + bid * 32 + m], fmaxf(pooledv, 0.f));
    }
    vmem_fence();
    __syncthreads();
    if (tid == 0) a_st(&flagH[gid * 16 + bid], 600u);

    const int beta = blk >> 2, qq = blk & 3;
    const int gidb = blk >> 4;  // group owning batch beta
    if (w == 0) {
        bool done = lane >= 16;
        while (!__all(done)) {
            if (!done) done = (a_ld(&flagH[gidb * 16 + lane]) >= 600u);
            if (!__all(done)) __builtin_amdgcn_s_sleep(1);
        }
    }
    __syncthreads();
    float* stage = (float*)&lds_h[0][0];
    stage[tid] = a_ldf(&pooled_g[(size_t)beta * 512 + tid]);
    __syncthreads();
    {
        int col = qq * 128 + (tid & 127), kc = tid >> 7;
        float p = 0.f;
        for (int k = kc * 128; k < kc * 128 + 128; ++k) p += stage[k] * W1[(size_t)k * 512 + col];
        float* redF = (float*)&outA[0][0];
        redF[kc * 128 + (tid & 127)] = p;
        __syncthreads();
        if (tid < 128) {
            int c2 = qq * 128 + tid;
            float s = redF[tid] + redF[128 + tid] + redF[256 + tid] + redF[384 + tid] + b1[c2];
            a_stf(&fc1_g[(size_t)beta * 512 + c2], s);
        }
    }
    vmem_fence();
    __syncthreads();
    if (tid == 0) a_st(&flagF[blk], 1u);

    if (qq == 0) {
        if (w == 0) {
            bool done = lane >= 4;
            while (!__all(done)) {
                if (!done) done = (a_ld(&flagF[blk + lane]) >= 1u);
                if (!__all(done)) __builtin_amdgcn_s_sleep(1);
            }
        }
        __syncthreads();
        stage[tid] = a_ldf(&fc1_g[(size_t)beta * 512 + tid]);
        __syncthreads();
        float* red2 = (float*)&outB[0][0];
        if (tid < 160) {
            int cls = tid >> 4, kc = tid & 15;
            float p = 0.f;
            for (int k = kc * 32; k < kc * 32 + 32; ++k) p += stage[k] * W2[k * 10 + cls];
            red2[tid] = p;
        }
        __syncthreads();
        if (tid < 10) {
            float s = b2[tid];
            #pragma unroll
            for (int j = 0; j < 16; ++j) s += red2[tid * 16 + j];
            out[beta * 10 + tid] = s;
        }
    }
}

extern "C" void kernel_launch(void* const* d_in, const int* in_sizes, int n_in,
                              void* d_out, int out_size, void* d_ws, size_t ws_size,
                              hipStream_t stream) {
    const int*   x   = (const int*)d_in[0];
    const float* emb = (const float*)d_in[1];
    const float* Wq  = (const float*)d_in[2];
    const float* Wx  = (const float*)d_in[3];
    const float* Wh  = (const float*)d_in[4];
    const float* bx  = (const float*)d_in[5];
    const float* bh  = (const float*)d_in[6];
    const float* W1  = (const float*)d_in[7];
    const float* b1  = (const float*)d_in[8];
    const float* W2  = (const float*)d_in[9];
    const float* b2  = (const float*)d_in[10];
    uint4* wsp = (uint4*)d_ws;
    float* outp = (float*)d_out;

    hipLaunchKernelGGL(pack_weights, dim3(896), dim3(256), 0, stream, Wq, Wx, Wh, wsp);
    hipMemsetAsync((char*)d_ws + SYNC_OFF, 0, 134144, stream);

    void* args[] = { (void*)&x, (void*)&emb, (void*)&wsp, (void*)&bx, (void*)&bh,
                     (void*)&W1, (void*)&b1, (void*)&W2, (void*)&b2, (void*)&outp };
    hipError_t e = hipLaunchCooperativeKernel((void*)gru_scan, dim3(256), dim3(THREADS),
                                              args, 0, stream);
    if (e != hipSuccess) {
        hipLaunchKernelGGL(gru_scan, dim3(256), dim3(THREADS), 0, stream,
                           x, emb, wsp, bx, bh, W1, b1, W2, b2, outp);
    }
}

// Round 8
// 3652.876 us; speedup vs baseline: 1.9432x; 1.9432x over previous
//
#include <hip/hip_runtime.h>
#include <hip/hip_fp16.h>

typedef __attribute__((ext_vector_type(2))) _Float16 half2v;
typedef __attribute__((ext_vector_type(2))) __fp16   fp16x2;

#define SEQ     512
#define THREADS 512

// ws layout (uint4 units): Wq col-packed [64][512] @0; Wx [64][1536] @32768; Wh @131072
#define WQ_OFF   0
#define WX_OFF   32768
#define WH_OFF   131072
#define SYNC_OFF 3670016
// sync region (bytes): flagH u32[256]@0 ; flagS u32[256]@1024 ;
// Hbuf u32[2][64][256]@2048 (131072) ; Pbuf f32[2][8][32][24]@133120 ;
// pooled f32[64][512]@182272 ; fc1 f32[64][512]@313344

__device__ inline unsigned int pack2f16(float a, float b) {
    fp16x2 p = __builtin_amdgcn_cvt_pkrtz(a, b);
    return __builtin_bit_cast(unsigned int, p);
}
__device__ inline float fdot2u(unsigned int a, unsigned int b, float acc) {
    return __builtin_amdgcn_fdot2(__builtin_bit_cast(half2v, a),
                                  __builtin_bit_cast(half2v, b), acc, false);
}
__device__ inline float dot4(uint4 h, uint4 w, float acc) {
    acc = fdot2u(h.x, w.x, acc); acc = fdot2u(h.y, w.y, acc);
    acc = fdot2u(h.z, w.z, acc); acc = fdot2u(h.w, w.w, acc);
    return acc;
}
__device__ inline float fsigmoid(float x) { return 1.f / (1.f + __expf(-x)); }
__device__ inline float ftanhf(float x) {
    float e = __expf(-2.f * fabsf(x));
    float t = (1.f - e) / (1.f + e);
    return copysignf(t, x);
}
__device__ inline void vmem_fence() { asm volatile("s_waitcnt vmcnt(0)" ::: "memory"); }
__device__ inline unsigned a_ld(unsigned* p) {
    return __hip_atomic_load(p, __ATOMIC_RELAXED, __HIP_MEMORY_SCOPE_AGENT);
}
__device__ inline void a_st(unsigned* p, unsigned v) {
    __hip_atomic_store(p, v, __ATOMIC_RELAXED, __HIP_MEMORY_SCOPE_AGENT);
}
__device__ inline float a_ldf(float* p) {
    return __hip_atomic_load(p, __ATOMIC_RELAXED, __HIP_MEMORY_SCOPE_AGENT);
}
__device__ inline void a_stf(float* p, float v) {
    __hip_atomic_store(p, v, __ATOMIC_RELAXED, __HIP_MEMORY_SCOPE_AGENT);
}

__global__ __launch_bounds__(256)
void pack_weights(const float* __restrict__ Wq,
                  const float* __restrict__ Wx,
                  const float* __restrict__ Wh,
                  uint4* __restrict__ ws) {
    int tid = blockIdx.x * blockDim.x + threadIdx.x;  // 0 .. 229375
    const float* src; uint4* dst; int C, idx;
    if (tid < 64 * 512)                  { src = Wq; dst = ws;          C = 512;  idx = tid; }
    else if (tid < 64 * 512 + 64 * 1536) { src = Wx; dst = ws + WX_OFF; C = 1536; idx = tid - 64 * 512; }
    else                                 { src = Wh; dst = ws + WH_OFF; C = 1536; idx = tid - (64 * 512 + 64 * 1536); }
    int m4 = idx / C;
    int c  = idx - m4 * C;
    const float* s = src + (size_t)(m4 * 8) * C + c;
    uint4 o;
    o.x = pack2f16(s[0 * (size_t)C], s[1 * (size_t)C]);
    o.y = pack2f16(s[2 * (size_t)C], s[3 * (size_t)C]);
    o.z = pack2f16(s[4 * (size_t)C], s[5 * (size_t)C]);
    o.w = pack2f16(s[6 * (size_t)C], s[7 * (size_t)C]);
    dst[idx] = o;
}

// 256 blocks. gid = blk & 7 (XCD-local groups), bid = blk >> 3. Group owns batches
// 8*gid..+8; block owns q-cols [bid*16,+16), gate cols [bid*16,+16) per gate.
// GEMM-gx replaced by h-independent per-head window GEMM (u_pk, 3-slot rolling).
__global__ __launch_bounds__(THREADS)
void gru_scan(const int* __restrict__ xtok, const float* __restrict__ emb,
              const uint4* __restrict__ wsp, const float* __restrict__ bx,
              const float* __restrict__ bh, const float* __restrict__ W1,
              const float* __restrict__ b1, const float* __restrict__ W2,
              const float* __restrict__ b2, float* __restrict__ out)
{
    const int blk  = blockIdx.x;
    const int gid  = blk & 7;
    const int bid  = blk >> 3;
    const int tid  = threadIdx.x;
    const int lane = tid & 63;
    const int wid  = tid >> 6;
    const int colsub = lane & 7;
    const int bp     = (lane >> 3) & 3;
    const int chsub  = lane >> 5;

    char* syncb = (char*)wsp + SYNC_OFF;
    unsigned* flagH = (unsigned*)syncb;
    unsigned* flagS = (unsigned*)(syncb + 1024);
    unsigned* Hbuf  = (unsigned*)(syncb + 2048);
    float* Pbuf     = (float*)(syncb + 133120);
    float* pooled_g = (float*)(syncb + 182272);
    float* fc1_g    = (float*)(syncb + 313344);

    __shared__ uint4 lds_W [64][65];       // cols 0..15 Wq-slice, 16..63 Wh-slice
    __shared__ uint4 lds_Wx[64][49];       // 48 Wx cols
    __shared__ uint4 lds_h4[8][65];        // dual-use: win row t (pre-B0) / h(t-1)
    __shared__ unsigned u_pk[3][8][48][4]; // per-head win@Wx partials, f16 pairs (b, b+4)
    __shared__ float redQf[1152];          // GEMM-q partials; then ghsum/gxsum
    __shared__ float redH[8][48][9];       // GEMM-gh partials (per head chunk)
    __shared__ float a_all[8][8][3];

    // ---- persistent weight slices -> LDS ----
    for (int i = tid; i < 64 * 64; i += THREADS) {
        int ch = i >> 6, cl = i & 63;
        uint4 v;
        if (cl < 16) v = wsp[WQ_OFF + ch * 512 + bid * 16 + cl];
        else { int g = (cl - 16) >> 4, c = (cl - 16) & 15;
               v = wsp[WH_OFF + ch * 1536 + g * 512 + bid * 16 + c]; }
        lds_W[ch][cl] = v;
    }
    for (int i = tid; i < 64 * 48; i += THREADS) {
        int ch = i / 48, cl = i - ch * 48;
        int g = cl >> 4, c = cl & 15;
        lds_Wx[ch][cl] = wsp[WX_OFF + ch * 1536 + g * 512 + bid * 16 + c];
    }

    float bxr = 0, bxz = 0, bxn = 0, bhr = 0, bhz = 0, bhn = 0;
    if (tid < 128) {
        int c = tid >> 3, cg = bid * 16 + c;
        bxr = bx[cg]; bxz = bx[512 + cg]; bxn = bx[1024 + cg];
        bhr = bh[cg]; bhz = bh[512 + cg]; bhn = bh[1024 + cg];
    }

    const int gb = gid * 8 + wid;
    // pre-loop: win row 0 -> lds_h4 ; zero u slots 1,2 (rows -2,-1)
    {
        int tk = xtok[gb * SEQ];
        const float4* p = (const float4*)(emb + (size_t)tk * 512 + lane * 8);
        float4 ra = p[0], rb = p[1];
        uint4 pk;
        pk.x = pack2f16(ra.x, ra.y); pk.y = pack2f16(ra.z, ra.w);
        pk.z = pack2f16(rb.x, rb.y); pk.w = pack2f16(rb.z, rb.w);
        lds_h4[wid][lane] = pk;
        unsigned* up = &u_pk[0][0][0][0];
        for (int i = tid; i < 3072; i += THREADS) up[1536 + i] = 0u;
    }
    float hprev = 0.f, pooledv = 0.f;
    __syncthreads();

    for (int t = 0; t < SEQ; ++t) {
        const int par = t & 1;
        const int slot = t % 3;

        // ---- prefetch win row t+1 (regs) + winv slices for scores ----
        int tnext = (t + 1 < SEQ) ? (t + 1) : t;
        int tkn = xtok[gb * SEQ + tnext];
        const float4* pn = (const float4*)(emb + (size_t)tkn * 512 + lane * 8);
        float4 r3a = pn[0], r3b = pn[1];

        float winv[16];
        int b3 = 0, g3 = 0, trow = -1;
        if (wid == 0 && lane < 24) {
            b3 = lane / 3; g3 = lane - b3 * 3;
            trow = t - 2 + g3;
            int tok = (trow >= 0) ? xtok[(gid * 8 + b3) * SEQ + trow] : -1;
            if (tok >= 0) {
                const float* er = emb + (size_t)tok * 512 + bid * 16;
                #pragma unroll
                for (int d = 0; d < 16; ++d) winv[d] = er[d];
            } else {
                #pragma unroll
                for (int d = 0; d < 16; ++d) winv[d] = 0.f;
            }
        }

        // ---- Phase U: u_pk[slot] = (win row t) @ Wx, per-head partials ----
        {
            float acu[12];
            #pragma unroll
            for (int i = 0; i < 12; ++i) acu[i] = 0.f;
            int ch0 = wid * 8 + chsub * 4;
            #pragma unroll
            for (int i = 0; i < 4; ++i) {
                int ch = ch0 + i;
                uint4 c0 = lds_h4[bp][ch], c1 = lds_h4[bp + 4][ch];
                #pragma unroll
                for (int j = 0; j < 6; ++j) {
                    uint4 w = lds_Wx[ch][colsub + 8 * j];
                    acu[j]     = dot4(c0, w, acu[j]);
                    acu[6 + j] = dot4(c1, w, acu[6 + j]);
                }
            }
            #pragma unroll
            for (int i = 0; i < 12; ++i) acu[i] += __shfl_xor(acu[i], 32);
            if (chsub == 0) {
                #pragma unroll
                for (int j = 0; j < 6; ++j)
                    u_pk[slot][wid][colsub + 8 * j][bp] = pack2f16(acu[j], acu[6 + j]);
            }
        }

        // ---- wave0: wait h(t-1) from all 32 blocks ----
        if (wid == 0) {
            bool done = lane >= 32;
            while (!__all(done)) {
                if (!done) done = (a_ld(&flagH[gid * 32 + lane]) >= (unsigned)t);
                if (!__all(done)) __builtin_amdgcn_s_sleep(1);
            }
        }
        __syncthreads();                                   // B0

        // ---- load h(t-1) -> lds_h4 (overwrites win; U done reading) ----
        {
            int bb = tid >> 6, c4 = tid & 63;
            unsigned* s = Hbuf + (size_t)(par ^ 1) * 16384 + (gid * 8 + bb) * 256 + c4 * 4;
            uint4 v;
            v.x = a_ld(s); v.y = a_ld(s + 1); v.z = a_ld(s + 2); v.w = a_ld(s + 3);
            lds_h4[bb][c4] = v;
        }
        __syncthreads();                                   // B2

        // ---- GEMM-q (16 cols) ----
        {
            float aq0 = 0, aq1 = 0, aq2 = 0, aq3 = 0;
            int ch0 = wid * 8 + chsub * 4;
            #pragma unroll
            for (int i = 0; i < 4; ++i) {
                int ch = ch0 + i;
                uint4 h0 = lds_h4[bp][ch], h1 = lds_h4[bp + 4][ch];
                uint4 w0 = lds_W[ch][colsub], w1 = lds_W[ch][colsub + 8];
                aq0 = dot4(h0, w0, aq0); aq1 = dot4(h0, w1, aq1);
                aq2 = dot4(h1, w0, aq2); aq3 = dot4(h1, w1, aq3);
            }
            aq0 += __shfl_xor(aq0, 32); aq1 += __shfl_xor(aq1, 32);
            aq2 += __shfl_xor(aq2, 32); aq3 += __shfl_xor(aq3, 32);
            if (chsub == 0) {
                redQf[(wid * 16 + colsub) * 9 + bp]         = aq0;
                redQf[(wid * 16 + colsub + 8) * 9 + bp]     = aq1;
                redQf[(wid * 16 + colsub) * 9 + bp + 4]     = aq2;
                redQf[(wid * 16 + colsub + 8) * 9 + bp + 4] = aq3;
            }
        }
        __syncthreads();                                   // B3

        // ---- wave0: score chain | waves1-7: GEMM-gh (wave7 also head 0) ----
        if (wid == 0) {
            if (lane < 24) {
                float s = 0.f;
                if (trow >= 0) {
                    #pragma unroll
                    for (int d = 0; d < 16; ++d) {
                        float q = redQf[d * 9 + b3];
                        #pragma unroll
                        for (int k = 1; k < 8; ++k) q += redQf[(k * 16 + d) * 9 + b3];
                        s += winv[d] * q;
                    }
                }
                a_stf(&Pbuf[(size_t)((par * 8 + gid) * 32 + bid) * 24 + b3 * 3 + g3], s);
            }
            vmem_fence();
            if (lane == 0) a_st(&flagS[gid * 32 + bid], (unsigned)(t + 1));
            bool done = lane >= 32;
            while (!__all(done)) {
                if (!done) done = (a_ld(&flagS[gid * 32 + lane]) >= (unsigned)(t + 1));
                if (!__all(done)) __builtin_amdgcn_s_sleep(1);
            }
            {
                int bb = lane >> 3, n = lane & 7;
                float* pb = Pbuf + (size_t)(par * 8 + gid) * 32 * 24;
                float sc0 = 0, sc1 = 0, sc2 = 0;
                #pragma unroll
                for (int j = 0; j < 4; ++j) {
                    float* pj = pb + (n * 4 + j) * 24 + bb * 3;
                    sc0 += a_ldf(pj); sc1 += a_ldf(pj + 1); sc2 += a_ldf(pj + 2);
                }
                sc0 *= 0.125f; sc1 *= 0.125f; sc2 *= 0.125f;
                float mx = fmaxf(sc0, fmaxf(sc1, sc2));
                float e0 = __expf(sc0 - mx), e1 = __expf(sc1 - mx), e2 = __expf(sc2 - mx);
                float inv = 1.f / (e0 + e1 + e2);
                a_all[bb][n][0] = e0 * inv; a_all[bb][n][1] = e1 * inv; a_all[bb][n][2] = e2 * inv;
            }
        } else {
            #pragma unroll 1
            for (int rep = 0; rep < 2; ++rep) {
                int k = (rep == 0) ? wid : 0;
                if (rep == 1 && wid != 7) break;
                float ag[12];
                #pragma unroll
                for (int i = 0; i < 12; ++i) ag[i] = 0.f;
                int ch0 = k * 8 + chsub * 4;
                #pragma unroll
                for (int i = 0; i < 4; ++i) {
                    int ch = ch0 + i;
                    uint4 h0 = lds_h4[bp][ch], h1 = lds_h4[bp + 4][ch];
                    #pragma unroll
                    for (int j = 0; j < 6; ++j) {
                        uint4 w = lds_W[ch][16 + colsub + 8 * j];
                        ag[j]     = dot4(h0, w, ag[j]);
                        ag[6 + j] = dot4(h1, w, ag[6 + j]);
                    }
                }
                #pragma unroll
                for (int i = 0; i < 12; ++i) ag[i] += __shfl_xor(ag[i], 32);
                if (chsub == 0) {
                    #pragma unroll
                    for (int j = 0; j < 6; ++j) {
                        redH[k][colsub + 8 * j][bp]     = ag[j];
                        redH[k][colsub + 8 * j][bp + 4] = ag[6 + j];
                    }
                }
            }
        }
        __syncthreads();                                   // B4

        // ---- combine (waves1-6): ghsum + gxsum ; all waves: pack win t+1 ----
        if (tid >= 64 && tid < 448) {
            int idx = tid - 64;
            int col = idx >> 3, bb = idx & 7;
            float ghs = redH[0][col][bb];
            #pragma unroll
            for (int k = 1; k < 8; ++k) ghs += redH[k][col][bb];
            float gxs = 0.f;
            int half = bb >> 2, bq = bb & 3;
            #pragma unroll
            for (int g = 0; g < 3; ++g) {
                int sg = (t + 1 + g) % 3;
                #pragma unroll
                for (int k = 0; k < 8; ++k) {
                    fp16x2 uv = __builtin_bit_cast(fp16x2, u_pk[sg][k][col][bq]);
                    gxs += a_all[bb][k][g] * (float)uv[half];
                }
            }
            redQf[col * 8 + bb]       = ghs;
            redQf[384 + col * 8 + bb] = gxs;
        }
        {
            uint4 pk;
            pk.x = pack2f16(r3a.x, r3a.y); pk.y = pack2f16(r3a.z, r3a.w);
            pk.z = pack2f16(r3b.x, r3b.y); pk.w = pack2f16(r3b.z, r3b.w);
            lds_h4[wid][lane] = pk;    // safe: gh finished reading h at B4
        }
        __syncthreads();                                   // B5

        // ---- GRU pointwise + h publish ----
        if (tid < 128) {
            int c = tid >> 3, bb = tid & 7;
            float ghr = redQf[c * 8 + bb]        + bhr;
            float ghz = redQf[(16 + c) * 8 + bb] + bhz;
            float ghn = redQf[(32 + c) * 8 + bb] + bhn;
            float gxr = redQf[384 + c * 8 + bb]        + bxr;
            float gxz = redQf[384 + (16 + c) * 8 + bb] + bxz;
            float gxn = redQf[384 + (32 + c) * 8 + bb] + bxn;
            float r = fsigmoid(gxr + ghr);
            float z = fsigmoid(gxz + ghz);
            float n = ftanhf(gxn + r * ghn);
            float hnew = (1.f - z) * n + z * hprev;
            hprev = hnew; pooledv += hnew;
            float hnext = __shfl_down(hnew, 8);
            if ((c & 1) == 0)
                a_st(&Hbuf[(size_t)par * 16384 + (gid * 8 + bb) * 256 + bid * 8 + (c >> 1)],
                     pack2f16(hnew, hnext));
        }
        vmem_fence();
        __syncthreads();                                   // B6
        if (tid == 0) a_st(&flagH[gid * 32 + bid], (unsigned)(t + 1));
    }

    // ======== epilogue: pooled -> relu -> FC1 -> FC2 ========
    float* stage = (float*)&lds_W[0][0];
    if (tid < 128) {
        int c = tid >> 3, bb = tid & 7;
        a_stf(&pooled_g[(gid * 8 + bb) * 512 + bid * 16 + c], fmaxf(pooledv, 0.f));
    }
    vmem_fence();
    __syncthreads();
    if (tid == 0) a_st(&flagS[gid * 32 + bid], (unsigned)(SEQ + 1));
    if (wid == 0) {
        bool done = lane >= 32;
        while (!__all(done)) {
            if (!done) done = (a_ld(&flagS[gid * 32 + lane]) >= (unsigned)(SEQ + 1));
            if (!__all(done)) __builtin_amdgcn_s_sleep(1);
        }
    }
    __syncthreads();

    for (int i = tid; i < 8 * 512; i += THREADS) {
        int bb = i >> 9, k = i & 511;
        stage[bb * 512 + k] = a_ldf(&pooled_g[(gid * 8 + bb) * 512 + k]);
    }
    __syncthreads();

    if (tid < 128) {
        int c = tid >> 3, bb = tid & 7;
        int cg = bid * 16 + c;
        const float* pr = stage + bb * 512;
        float acc1 = b1[cg];
        for (int k = 0; k < 512; ++k) acc1 += pr[k] * W1[(size_t)k * 512 + cg];
        a_stf(&fc1_g[(gid * 8 + bb) * 512 + cg], acc1);
    }
    vmem_fence();
    __syncthreads();
    if (tid == 0) a_st(&flagH[gid * 32 + bid], (unsigned)(SEQ + 2));

    if (bid == 0) {
        if (wid == 0) {
            bool done = lane >= 32;
            while (!__all(done)) {
                if (!done) done = (a_ld(&flagH[gid * 32 + lane]) >= (unsigned)(SEQ + 2));
                if (!__all(done)) __builtin_amdgcn_s_sleep(1);
            }
        }
        __syncthreads();
        for (int i = tid; i < 8 * 512; i += THREADS) {
            int bb = i >> 9, k = i & 511;
            stage[bb * 512 + k] = a_ldf(&fc1_g[(gid * 8 + bb) * 512 + k]);
        }
        __syncthreads();
        if (tid < 80) {
            int bb = tid / 10, cls = tid - bb * 10;
            const float* fr = stage + bb * 512;
            float a2 = b2[cls];
            for (int k = 0; k < 512; ++k) a2 += fr[k] * W2[k * 10 + cls];
            out[(gid * 8 + bb) * 10 + cls] = a2;
        }
    }
}

extern "C" void kernel_launch(void* const* d_in, const int* in_sizes, int n_in,
                              void* d_out, int out_size, void* d_ws, size_t ws_size,
                              hipStream_t stream) {
    const int*   x   = (const int*)d_in[0];
    const float* emb = (const float*)d_in[1];
    const float* Wq  = (const float*)d_in[2];
    const float* Wx  = (const float*)d_in[3];
    const float* Wh  = (const float*)d_in[4];
    const float* bx  = (const float*)d_in[5];
    const float* bh  = (const float*)d_in[6];
    const float* W1  = (const float*)d_in[7];
    const float* b1  = (const float*)d_in[8];
    const float* W2  = (const float*)d_in[9];
    const float* b2  = (const float*)d_in[10];
    uint4* wsp = (uint4*)d_ws;
    float* outp = (float*)d_out;

    hipLaunchKernelGGL(pack_weights, dim3(896), dim3(256), 0, stream, Wq, Wx, Wh, wsp);
    hipMemsetAsync((char*)d_ws + SYNC_OFF, 0, 182272, stream);

    void* args[] = { (void*)&x, (void*)&emb, (void*)&wsp, (void*)&bx, (void*)&bh,
                     (void*)&W1, (void*)&b1, (void*)&W2, (void*)&b2, (void*)&outp };
    hipError_t e = hipLaunchCooperativeKernel((void*)gru_scan, dim3(256), dim3(THREADS),
                                              args, 0, stream);
    if (e != hipSuccess) {
        hipLaunchKernelGGL(gru_scan, dim3(256), dim3(THREADS), 0, stream,
                           x, emb, wsp, bx, bh, W1, b1, W2, b2, outp);
    }
}